// Round 3
// baseline (5112.217 us; speedup 1.0000x reference)
//
#include <hip/hip_runtime.h>

// LanguageModel: embed -> 2x LSTM(1024) -> proj(32000) -> log_softmax
// B=32, S=128, HID=1024, VOC=32000.  Rows m = b*S + s (4096 rows).

#define SEQ   128
#define NBAT  32
#define HID   1024
#define VOC   32000
#define RBLK  128   // blocks in persistent recurrence kernel (<= 256 CUs)

typedef __attribute__((ext_vector_type(4))) float        f32x4;
typedef __attribute__((ext_vector_type(4))) unsigned int u32x4;
typedef __attribute__((ext_vector_type(2))) unsigned int u32x2;

__device__ __forceinline__ unsigned short f2bf(float f) {
    unsigned u = __builtin_bit_cast(unsigned, f);
    u += 0x7fffu + ((u >> 16) & 1u);          // RNE
    return (unsigned short)(u >> 16);
}
__device__ __forceinline__ unsigned pk2(float a, float b) {
    return (unsigned)f2bf(a) | ((unsigned)f2bf(b) << 16);
}
// inline-asm MFMA (verified convention: D[m][n] with n=lane&15 from B-rows,
// m=(lane>>4)*4+q from A-rows; A/B frag: row=lane&15, k=(lane>>4)*8 per 32-chunk).
__device__ __forceinline__ void mfma16(f32x4& d, u32x4 a, u32x4 b) {
    asm("v_mfma_f32_16x16x32_bf16 %0, %1, %2, %0" : "+v"(d) : "v"(a), "v"(b));
}
__device__ __forceinline__ void mfma_fence() {
    __builtin_amdgcn_sched_barrier(0);
    asm volatile("s_nop 7\ns_nop 7\ns_nop 7");
    __builtin_amdgcn_sched_barrier(0);
}

// ---------------- f32 -> bf16 bulk cast ----------------
__global__ void cast_bf16_k(const float* __restrict__ in,
                            unsigned short* __restrict__ out, int n4) {
    int i = blockIdx.x * blockDim.x + threadIdx.x;
    int stride = gridDim.x * blockDim.x;
    for (; i < n4; i += stride) {
        f32x4 v = ((const f32x4*)in)[i];
        u32x2 p = { pk2(v.x, v.y), pk2(v.z, v.w) };
        ((u32x2*)out)[i] = p;
    }
}

// ---------------- embedding gather (f32 -> bf16) ----------------
__global__ void gather_k(const int* __restrict__ tok, const float* __restrict__ emb,
                         unsigned short* __restrict__ xe) {
    int row = blockIdx.x;                       // b*S+s
    int t   = tok[row];
    const f32x4* src = (const f32x4*)(emb + (size_t)t * HID);
    u32x2*       dst = (u32x2*)(xe + (size_t)row * HID);
    int i = threadIdx.x;                        // 256 threads, 256 f32x4/row
    f32x4 v = src[i];
    u32x2 p = { pk2(v.x, v.y), pk2(v.z, v.w) };
    dst[i] = p;
}

// ---------------- 128x128-tile MFMA GEMM: C = A[M,1024] @ B[N,1024]^T + bias ----------------
// blockIdx.x -> M-tile (fast) so co-scheduled blocks share one B panel.
template<bool BF32>
__global__ __launch_bounds__(256, 2) void gemm_k(
    const unsigned short* __restrict__ A, const void* __restrict__ Bsrc,
    const float* __restrict__ bias1, const float* __restrict__ bias2,
    float* __restrict__ C, int N)
{
    __shared__ u32x4 As[128][8];
    __shared__ u32x4 Bs[128][8];
    const int tid  = threadIdx.x;
    const int lane = tid & 63, wid = tid >> 6;
    const int wm = (wid >> 1) * 64, wn = (wid & 1) * 64;
    const int m0 = blockIdx.x * 128, n0 = blockIdx.y * 128;
    const int r = tid >> 1, half = tid & 1;     // staging: 2 threads per tile-row
    f32x4 acc[4][4] = {};

    const unsigned short* Ar = A + (size_t)(m0 + r) * HID + half * 32;
    for (int kt = 0; kt < HID / 64; ++kt) {
        const int k0 = kt * 64;
        {
            const u32x4* s = (const u32x4*)(Ar + k0);
            #pragma unroll
            for (int c = 0; c < 4; ++c)
                As[r][(half * 4 + c) ^ (r & 7)] = s[c];
        }
        if constexpr (!BF32) {
            const u32x4* s = (const u32x4*)((const unsigned short*)Bsrc +
                              (size_t)(n0 + r) * HID + half * 32 + k0);
            #pragma unroll
            for (int c = 0; c < 4; ++c)
                Bs[r][(half * 4 + c) ^ (r & 7)] = s[c];
        } else {
            const f32x4* s = (const f32x4*)((const float*)Bsrc +
                              (size_t)(n0 + r) * HID + half * 32 + k0);
            #pragma unroll
            for (int c = 0; c < 4; ++c) {
                f32x4 v0 = s[2 * c], v1 = s[2 * c + 1];
                u32x4 p = { pk2(v0.x, v0.y), pk2(v0.z, v0.w),
                            pk2(v1.x, v1.y), pk2(v1.z, v1.w) };
                Bs[r][(half * 4 + c) ^ (r & 7)] = p;
            }
        }
        __syncthreads();
        #pragma unroll
        for (int h = 0; h < 2; ++h) {
            u32x4 af[4], bfr[4];
            #pragma unroll
            for (int i = 0; i < 4; ++i) {
                int ra = wm + i * 16 + (lane & 15);
                af[i]  = As[ra][(h * 4 + (lane >> 4)) ^ (ra & 7)];
                int rb = wn + i * 16 + (lane & 15);
                bfr[i] = Bs[rb][(h * 4 + (lane >> 4)) ^ (rb & 7)];
            }
            #pragma unroll
            for (int i = 0; i < 4; ++i)
                #pragma unroll
                for (int j = 0; j < 4; ++j)
                    mfma16(acc[i][j], af[i], bfr[j]);
        }
        __syncthreads();
    }
    mfma_fence();
    #pragma unroll
    for (int j = 0; j < 4; ++j) {
        int col = n0 + wn + j * 16 + (lane & 15);
        float bv = 0.f;
        if (bias1) bv += bias1[col];
        if (bias2) bv += bias2[col];
        #pragma unroll
        for (int i = 0; i < 4; ++i) {
            int mrow = m0 + wm + i * 16 + (lane >> 4) * 4;
            #pragma unroll
            for (int q = 0; q < 4; ++q)
                C[(size_t)(mrow + q) * N + col] = acc[i][j][q] + bv;
        }
    }
}

// ---------------- persistent 128-step LSTM recurrence ----------------
// RBLK=128 blocks x 256 threads; block owns 8 units x 4 gates = 32 Whh rows.
// Whh fragments live in 128 VGPRs for the whole kernel (loaded once, f32->bf16
// in-kernel); cell state c in a per-thread register; h read direct from
// global (L2/L3-hot); hand-rolled monotonic grid barrier between steps.
__global__ __launch_bounds__(256, 1) void lstm_pers(
    const float* __restrict__ X, const float* __restrict__ Whh,
    unsigned short* __restrict__ hseq, unsigned* __restrict__ bar)
{
    __shared__ float gl[32][33];                // [batch][gate-row n], +1 pad
    const int tid  = threadIdx.x;
    const int lane = tid & 63, wid = tid >> 6;
    const int m    = wid & 1;                   // batch half
    const int nh   = wid >> 1;                  // gate-row half
    const int u0   = blockIdx.x * 8;

    // ---- load this wave's 32 B-fragments of Whh into registers (once) ----
    const int n    = nh * 16 + (lane & 15);     // 0..31 within block
    const int grow = (n >> 3) * HID + u0 + (n & 7);
    const float* wr = Whh + (size_t)grow * HID + (lane >> 4) * 8;
    u32x4 wreg[32];
    #pragma unroll
    for (int kk = 0; kk < 32; ++kk) {
        f32x4 v0 = *(const f32x4*)(wr + kk * 32);
        f32x4 v1 = *(const f32x4*)(wr + kk * 32 + 4);
        u32x4 p = { pk2(v0.x, v0.y), pk2(v0.z, v0.w),
                    pk2(v1.x, v1.y), pk2(v1.z, v1.w) };
        wreg[kk] = p;
    }

    // per-lane A-fragment base: batch row (m*16 + lane&15), k-quarter lane>>4
    const unsigned short* hbase = hseq +
        (size_t)(m * 16 + (lane & 15)) * SEQ * HID + (lane >> 4) * 8;

    // cell-update mapping: thread -> (batch, unit j)
    const int batch = tid >> 3, j = tid & 7;
    const float* xb = X + (size_t)(batch * SEQ) * (4 * HID) + u0 + j;
    unsigned short* hw = hseq + (size_t)(batch * SEQ) * HID + u0 + j;
    float creg = 0.f;

    for (int t = 0; t < SEQ; ++t) {
        f32x4 acc_a = {}, acc_b = {};
        if (t > 0) {
            const unsigned short* hp = hbase + (size_t)(t - 1) * HID;
            #pragma unroll
            for (int kk = 0; kk < 32; kk += 2) {
                u32x4 a0 = *(const u32x4*)(hp + kk * 32);
                u32x4 a1 = *(const u32x4*)(hp + kk * 32 + 32);
                mfma16(acc_a, a0, wreg[kk]);
                mfma16(acc_b, a1, wreg[kk + 1]);
            }
        }
        mfma_fence();
        // gate exchange: D tile is [m-batch-half][this wave's 16 n-rows]
        #pragma unroll
        for (int q = 0; q < 4; ++q)
            gl[m * 16 + (lane >> 4) * 4 + q][nh * 16 + (lane & 15)]
                = acc_a[q] + acc_b[q];
        __syncthreads();
        // cell update (1 output per thread), c stays in register
        {
            const float* Xr = xb + (size_t)t * (4 * HID);
            float ig = gl[batch][j]      + Xr[0];
            float fg = gl[batch][8 + j]  + Xr[HID];
            float gg = gl[batch][16 + j] + Xr[2 * HID];
            float og = gl[batch][24 + j] + Xr[3 * HID];
            float si = 1.f / (1.f + __expf(-ig));
            float sf = 1.f / (1.f + __expf(-fg));
            float so = 1.f / (1.f + __expf(-og));
            float tg = tanhf(gg);
            creg = sf * creg + si * tg;
            hw[(size_t)t * HID] = f2bf(so * tanhf(creg));
        }
        // grid barrier (skip after last step; kernel end flushes)
        if (t < SEQ - 1) {
            __syncthreads();                    // all h-writes issued+drained
            if (tid == 0) {
                __hip_atomic_fetch_add(bar, 1u, __ATOMIC_RELEASE,
                                       __HIP_MEMORY_SCOPE_AGENT);
                const unsigned target = (unsigned)(t + 1) * (unsigned)gridDim.x;
                while (__hip_atomic_load(bar, __ATOMIC_RELAXED,
                                         __HIP_MEMORY_SCOPE_AGENT) < target)
                    __builtin_amdgcn_s_sleep(2);
                __threadfence();                // acquire: inv L1/L2
            }
            __syncthreads();
        }
    }
}

// ---------------- in-place log_softmax per row ----------------
__global__ __launch_bounds__(256) void lsm_k(float* __restrict__ out) {
    const int tid = threadIdx.x;
    float* p = out + (size_t)blockIdx.x * VOC;
    float m = -1e30f, s = 0.f;
    for (int i = tid; i < VOC / 4; i += 256) {
        f32x4 v = ((const f32x4*)p)[i];
        float vm = fmaxf(fmaxf(v.x, v.y), fmaxf(v.z, v.w));
        if (vm > m) { s *= __expf(m - vm); m = vm; }
        s += __expf(v.x - m) + __expf(v.y - m) + __expf(v.z - m) + __expf(v.w - m);
    }
    #pragma unroll
    for (int o = 32; o; o >>= 1) {
        float om = __shfl_xor(m, o), os = __shfl_xor(s, o);
        float M = fmaxf(m, om);
        s = s * __expf(m - M) + os * __expf(om - M);
        m = M;
    }
    __shared__ float rm[4], rs[4];
    if ((tid & 63) == 0) { rm[tid >> 6] = m; rs[tid >> 6] = s; }
    __syncthreads();
    float M = fmaxf(fmaxf(rm[0], rm[1]), fmaxf(rm[2], rm[3]));
    float S = rs[0] * __expf(rm[0] - M) + rs[1] * __expf(rm[1] - M)
            + rs[2] * __expf(rm[2] - M) + rs[3] * __expf(rm[3] - M);
    float lse = M + logf(S);
    for (int i = tid; i < VOC / 4; i += 256) {
        f32x4 v = ((const f32x4*)p)[i];
        v.x -= lse; v.y -= lse; v.z -= lse; v.w -= lse;
        ((f32x4*)p)[i] = v;
    }
}

extern "C" void kernel_launch(void* const* d_in, const int* in_sizes, int n_in,
                              void* d_out, int out_size, void* d_ws, size_t ws_size,
                              hipStream_t stream)
{
    (void)in_sizes; (void)n_in; (void)out_size; (void)ws_size;
    const int*   tok  = (const int*)d_in[0];
    const float* emb  = (const float*)d_in[1];
    const float* Wih1 = (const float*)d_in[2];
    const float* Whh1 = (const float*)d_in[3];
    const float* bih1 = (const float*)d_in[4];
    const float* bhh1 = (const float*)d_in[5];
    const float* Wih2 = (const float*)d_in[6];
    const float* Whh2 = (const float*)d_in[7];
    const float* bih2 = (const float*)d_in[8];
    const float* bhh2 = (const float*)d_in[9];
    const float* Wout = (const float*)d_in[10];
    const float* bout = (const float*)d_in[11];
    float* out = (float*)d_out;
    char*  ws  = (char*)d_ws;

    // ws layout (~41 MB)
    unsigned short* Wih1b = (unsigned short*)(ws + (0ull  << 20));
    unsigned short* Wih2b = (unsigned short*)(ws + (8ull  << 20));
    unsigned short* Xemb  = (unsigned short*)(ws + (16ull << 20));
    unsigned short* h1s   = (unsigned short*)(ws + (24ull << 20));
    unsigned short* h2s   = (unsigned short*)(ws + (32ull << 20));
    unsigned*       bar   = (unsigned*)(ws + (40ull << 20));
    // X1/X2 (64MB each, f32 gate pre-activations) live in d_out; the final
    // projection overwrites the whole 524MB region afterwards.
    float* X1 = out;
    float* X2 = out + (16ull << 20);

    const int n4w = (4 * HID * HID) / 4;
    cast_bf16_k<<<1024, 256, 0, stream>>>(Wih1, Wih1b, n4w);
    cast_bf16_k<<<1024, 256, 0, stream>>>(Wih2, Wih2b, n4w);
    gather_k<<<NBAT * SEQ, 256, 0, stream>>>(tok, emb, Xemb);

    // layer-1: batched input projection, then persistent recurrence
    gemm_k<false><<<dim3(32, 32), 256, 0, stream>>>(Xemb, Wih1b, bih1, bhh1, X1, 4 * HID);
    hipMemsetAsync(bar, 0, 128, stream);
    lstm_pers<<<RBLK, 256, 0, stream>>>(X1, Whh1, h1s, bar);

    // layer-2: batched input projection, then persistent recurrence
    gemm_k<false><<<dim3(32, 32), 256, 0, stream>>>(h1s, Wih2b, bih2, bhh2, X2, 4 * HID);
    hipMemsetAsync(bar, 0, 128, stream);
    lstm_pers<<<RBLK, 256, 0, stream>>>(X2, Whh2, h2s, bar);

    // output projection + log_softmax
    gemm_k<true><<<dim3(32, VOC / 128), 256, 0, stream>>>(h2s, Wout, bout, nullptr, out, VOC);
    lsm_k<<<NBAT * SEQ, 256, 0, stream>>>(out);
}